// Round 2
// baseline (96.217 us; speedup 1.0000x reference)
//
#include <hip/hip_runtime.h>
#include <hip/hip_bf16.h>

// Problem constants (B=8, S=512, D=256, M=64, DE=256, H=8, DH=32).
// Key insight: activity = attn.mean over (H,S) == 1/S = 1/512 < 0.1 always
// (softmax rows sum to 1), so entity_mask == 0 and the returned graph == 0
// exactly. Only `entities` requires compute; refinement/gate MLPs are dead.

#define NS 512
#define ND 256
#define NB 8
#define NM 64
#define NH 8

// ---------------- x = emb + pos ----------------
__global__ __launch_bounds__(256) void add_pos_kernel(const float* __restrict__ emb,
        const float* __restrict__ pos, float* __restrict__ x) {
    int i = blockIdx.x * 256 + threadIdx.x;      // float4 index, total B*S*D/4 = 262144
    int dq = i & 63;                              // D/4 = 64 float4 per row
    int s  = (i >> 6) & 511;
    float4 e = ((const float4*)emb)[i];
    float4 p = ((const float4*)pos)[(s << 6) + dq];
    float4 r; r.x = e.x + p.x; r.y = e.y + p.y; r.z = e.z + p.z; r.w = e.w + p.w;
    ((float4*)x)[i] = r;
}

// ---------------- zero the graph+mask tail of d_out (133 KB) ----------------
// hipMemsetAsync's fillBufferAligned took ~40us for this region; a plain
// store kernel is launch-overhead bound (~3us).
__global__ __launch_bounds__(256) void zero_tail_kernel(float4* __restrict__ p, int n4) {
    int i = blockIdx.x * 256 + threadIdx.x;
    if (i < n4) p[i] = make_float4(0.f, 0.f, 0.f, 0.f);
}

// ---------------- q = (lib @ wq) * rsqrt(DH) ----------------
__global__ __launch_bounds__(256) void qproj_kernel(const float* __restrict__ lib,
        const float* __restrict__ wq, float* __restrict__ q) {
    int m = blockIdx.x;            // 64
    int t = threadIdx.x;           // 256 output cols (h*32+dh)
    __shared__ float row[256];
    row[t] = lib[m * 256 + t];
    __syncthreads();
    float acc = 0.f;
    #pragma unroll 8
    for (int d = 0; d < 256; ++d) acc = fmaf(row[d], wq[d * 256 + t], acc);
    q[m * 256 + t] = acc * 0.17677669529663687f;   // 1/sqrt(32)
}

// ---------------- generic fp32 tiled GEMM: C[M,N] = A[M,K] @ B[K,N] ----------------
// BM=BN=64, BK=16, 256 threads, 4x4 micro-tile. grid=(M/64, N/64)
__global__ __launch_bounds__(256) void gemm_f32_kernel(const float* __restrict__ A,
        const float* __restrict__ Bm, float* __restrict__ C, int N, int K) {
    __shared__ float As[16][64];     // [k][m] (transposed A tile)
    __shared__ float Bs[16][64];     // [k][n]
    const int tid  = threadIdx.x;
    const int tr   = tid >> 4, tc = tid & 15;
    const int arow = tid >> 2, akq = (tid & 3) << 2;
    const int brow = tid >> 4, bnq = (tid & 15) << 2;
    float c[4][4] = {};
    const float* Ap = A + (size_t)(blockIdx.x * 64 + arow) * K + akq;
    const float* Bp = Bm + (size_t)brow * N + blockIdx.y * 64 + bnq;
    for (int k0 = 0; k0 < K; k0 += 16) {
        float4 av = *(const float4*)(Ap + k0);
        float4 bv = *(const float4*)(Bp + (size_t)k0 * N);
        As[akq    ][arow] = av.x;
        As[akq + 1][arow] = av.y;
        As[akq + 2][arow] = av.z;
        As[akq + 3][arow] = av.w;
        *(float4*)&Bs[brow][bnq] = bv;
        __syncthreads();
        #pragma unroll
        for (int kk = 0; kk < 16; ++kk) {
            float4 a4 = *(const float4*)&As[kk][tr << 2];
            float4 b4 = *(const float4*)&Bs[kk][tc << 2];
            float aa[4] = {a4.x, a4.y, a4.z, a4.w};
            float bb[4] = {b4.x, b4.y, b4.z, b4.w};
            #pragma unroll
            for (int i = 0; i < 4; ++i)
                #pragma unroll
                for (int j = 0; j < 4; ++j)
                    c[i][j] = fmaf(aa[i], bb[j], c[i][j]);
        }
        __syncthreads();
    }
    float* Cp = C + (size_t)(blockIdx.x * 64 + (tr << 2)) * N + blockIdx.y * 64 + (tc << 2);
    #pragma unroll
    for (int i = 0; i < 4; ++i)
        *(float4*)(Cp + (size_t)i * N) = make_float4(c[i][0], c[i][1], c[i][2], c[i][3]);
}

// ---------------- attention partials ----------------
// grid (b*H+h, s-quarter), 256 threads = 4 waves. lane = m (64 queries),
// each wave covers 32 s-rows with online softmax; k/v rows are wave-uniform.
__global__ __launch_bounds__(256) void attn_partial_kernel(const float* __restrict__ q,
        const float* __restrict__ k, const float* __restrict__ v, float* __restrict__ part) {
    const int bh = blockIdx.x;            // 0..63
    const int sq = blockIdx.y;            // 0..3
    const int b = bh >> 3, h = bh & 7;
    const int w = threadIdx.x >> 6;       // wave 0..3
    const int m = threadIdx.x & 63;       // query index
    const int s0 = sq * 128 + w * 32;

    float qr[32];
    {
        const float4* qp = (const float4*)(q + m * 256 + h * 32);
        #pragma unroll
        for (int u = 0; u < 8; ++u) {
            float4 t = qp[u];
            qr[4*u] = t.x; qr[4*u+1] = t.y; qr[4*u+2] = t.z; qr[4*u+3] = t.w;
        }
    }
    const float* kbase = k + ((size_t)(b * 512 + s0)) * 256 + h * 32;
    const float* vbase = v + ((size_t)(b * 512 + s0)) * 256 + h * 32;

    float Mx = -1e30f, sum = 0.f, acc[32];
    #pragma unroll
    for (int dh = 0; dh < 32; ++dh) acc[dh] = 0.f;

    #pragma unroll
    for (int cc = 0; cc < 4; ++cc) {          // 4 chunks of 8 s-rows
        float sc[8];
        #pragma unroll
        for (int i = 0; i < 8; ++i) {
            const float4* kr = (const float4*)(kbase + (size_t)(cc * 8 + i) * 256);
            float dsum = 0.f;
            #pragma unroll
            for (int u = 0; u < 8; ++u) {
                float4 kv = kr[u];
                dsum = fmaf(qr[4*u],   kv.x, dsum);
                dsum = fmaf(qr[4*u+1], kv.y, dsum);
                dsum = fmaf(qr[4*u+2], kv.z, dsum);
                dsum = fmaf(qr[4*u+3], kv.w, dsum);
            }
            sc[i] = dsum;
        }
        float cm = sc[0];
        #pragma unroll
        for (int i = 1; i < 8; ++i) cm = fmaxf(cm, sc[i]);
        float nm = fmaxf(Mx, cm);
        float f = __expf(Mx - nm);            // first iter: exp(-1e30) -> 0
        sum *= f;
        #pragma unroll
        for (int dh = 0; dh < 32; ++dh) acc[dh] *= f;
        #pragma unroll
        for (int i = 0; i < 8; ++i) {
            float p = __expf(sc[i] - nm);
            sum += p;
            const float4* vr = (const float4*)(vbase + (size_t)(cc * 8 + i) * 256);
            #pragma unroll
            for (int u = 0; u < 8; ++u) {
                float4 vv = vr[u];
                acc[4*u]   = fmaf(p, vv.x, acc[4*u]);
                acc[4*u+1] = fmaf(p, vv.y, acc[4*u+1]);
                acc[4*u+2] = fmaf(p, vv.z, acc[4*u+2]);
                acc[4*u+3] = fmaf(p, vv.w, acc[4*u+3]);
            }
        }
        Mx = nm;
    }
    // partial record: 36 floats (32 acc, M, sum, 2 pad) per (bh, sq, w, m)
    float* pp = part + ((size_t)((bh * 4 + sq) * 4 + w) * 64 + m) * 36;
    #pragma unroll
    for (int u = 0; u < 8; ++u)
        *(float4*)(pp + 4 * u) = make_float4(acc[4*u], acc[4*u+1], acc[4*u+2], acc[4*u+3]);
    pp[32] = Mx; pp[33] = sum;
}

// ---------------- combine 16 partials -> ctx[b,m,h,dh] ----------------
__global__ __launch_bounds__(256) void attn_combine_kernel(const float* __restrict__ part,
        float* __restrict__ ctx) {
    const int bh = blockIdx.x;            // 0..63
    const int b = bh >> 3, h = bh & 7;
    const int t = threadIdx.x;
    const int m = t >> 2, g = t & 3;      // 4 threads per m, 8 dh each
    const float* pb = part + (size_t)bh * 16 * 64 * 36 + m * 36;
    float Mj[16], Sj[16];
    float Mx = -1e30f;
    #pragma unroll
    for (int j = 0; j < 16; ++j) {
        Mj[j] = pb[(size_t)j * 64 * 36 + 32];
        Sj[j] = pb[(size_t)j * 64 * 36 + 33];
        Mx = fmaxf(Mx, Mj[j]);
    }
    float wgt[16]; float Ssum = 0.f;
    #pragma unroll
    for (int j = 0; j < 16; ++j) { wgt[j] = __expf(Mj[j] - Mx); Ssum = fmaf(wgt[j], Sj[j], Ssum); }
    float inv = 1.f / Ssum;
    float* op = ctx + ((size_t)(b * 64 + m)) * 256 + h * 32 + g * 8;
    #pragma unroll
    for (int u = 0; u < 8; ++u) {
        float num = 0.f;
        #pragma unroll
        for (int j = 0; j < 16; ++j) num = fmaf(wgt[j], pb[(size_t)j * 64 * 36 + g * 8 + u], num);
        op[u] = num * inv;
    }
}

extern "C" void kernel_launch(void* const* d_in, const int* in_sizes, int n_in,
                              void* d_out, int out_size, void* d_ws, size_t ws_size,
                              hipStream_t stream) {
    const float* emb = (const float*)d_in[0];
    const float* lib = (const float*)d_in[2];
    const float* pos = (const float*)d_in[3];
    const float* wq  = (const float*)d_in[4];
    const float* wk  = (const float*)d_in[5];
    const float* wv  = (const float*)d_in[6];
    const float* wo  = (const float*)d_in[7];
    float* out = (float*)d_out;

    float* ws  = (float*)d_ws;
    float* kbuf = ws;                       // 4096*256 = 1,048,576
    float* vbuf = kbuf + 1048576;           // 1,048,576
    float* qbuf = vbuf + 1048576;           // 16,384
    float* ctx  = qbuf + 16384;             // 131,072
    float* xbuf = ctx + 131072;             // 1,048,576
    float* part = xbuf;                     // aliases x (dead after GEMMs); 2,359,296

    add_pos_kernel<<<1024, 256, 0, stream>>>(emb, pos, xbuf);
    qproj_kernel<<<64, 256, 0, stream>>>(lib, wq, qbuf);

    // graph (32768 floats) + entity_mask (512 floats) are exactly zero.
    // 33280 floats = 8320 float4 -> 33 blocks. Runs concurrently with the rest.
    zero_tail_kernel<<<33, 256, 0, stream>>>((float4*)(out + 131072), 8320);

    dim3 gkv(64, 4);   // M=4096/64, N=256/64
    gemm_f32_kernel<<<gkv, 256, 0, stream>>>(xbuf, wk, kbuf, 256, 256);
    gemm_f32_kernel<<<gkv, 256, 0, stream>>>(xbuf, wv, vbuf, 256, 256);

    attn_partial_kernel<<<dim3(64, 4), 256, 0, stream>>>(qbuf, kbuf, vbuf, part);
    attn_combine_kernel<<<64, 256, 0, stream>>>(part, ctx);

    // entities = ctx[512,256] @ wo[256,256] -> d_out[0:131072]
    gemm_f32_kernel<<<dim3(8, 4), 256, 0, stream>>>(ctx, wo, out, 256, 256);
}

// Round 4
// 84.591 us; speedup vs baseline: 1.1374x; 1.1374x over previous
//
#include <hip/hip_runtime.h>
#include <hip/hip_bf16.h>

// Problem constants (B=8, S=512, D=256, M=64, DE=256, H=8, DH=32).
// Key insight: activity = attn.mean over (H,S) == 1/S = 1/512 < 0.1 always
// (softmax rows sum to 1), so entity_mask == 0 and the returned graph == 0
// exactly. Only `entities` requires compute; refinement/gate MLPs are dead.
//
// Round 4: fix round-3's A-tile staging bug (only half the 128x32 tile was
// written to LDS -> NaN). Each thread now stages 16 ushorts (2x short8).

typedef unsigned short ushort_t;
typedef __attribute__((ext_vector_type(8))) short short8;
typedef __attribute__((ext_vector_type(4))) float f32x4;

__device__ __forceinline__ ushort_t f2bf(float f) {
    unsigned u = __builtin_bit_cast(unsigned, f);
    unsigned r = (u + 0x7fff + ((u >> 16) & 1)) >> 16;   // RNE
    return (ushort_t)r;
}
__device__ __forceinline__ float bf2f(ushort_t h) {
    return __builtin_bit_cast(float, (unsigned)h << 16);
}

// ---------------- x = emb + pos -> bf16 hi/lo split ----------------
__global__ __launch_bounds__(256) void add_pos_cvt_kernel(const float* __restrict__ emb,
        const float* __restrict__ pos, ushort_t* __restrict__ xh, ushort_t* __restrict__ xl) {
    int i = blockIdx.x * 256 + threadIdx.x;      // float4 index, total 262144
    int dq = i & 63;                              // D/4 = 64 float4 per row
    int s  = (i >> 6) & 511;
    float4 e = ((const float4*)emb)[i];
    float4 p = ((const float4*)pos)[(s << 6) + dq];
    float v[4] = {e.x + p.x, e.y + p.y, e.z + p.z, e.w + p.w};
    unsigned h01, h23, l01, l23;
    {
        ushort_t h0 = f2bf(v[0]), h1 = f2bf(v[1]), h2 = f2bf(v[2]), h3 = f2bf(v[3]);
        ushort_t l0 = f2bf(v[0] - bf2f(h0)), l1 = f2bf(v[1] - bf2f(h1));
        ushort_t l2 = f2bf(v[2] - bf2f(h2)), l3 = f2bf(v[3] - bf2f(h3));
        h01 = (unsigned)h0 | ((unsigned)h1 << 16); h23 = (unsigned)h2 | ((unsigned)h3 << 16);
        l01 = (unsigned)l0 | ((unsigned)l1 << 16); l23 = (unsigned)l2 | ((unsigned)l3 << 16);
    }
    ((uint2*)xh)[i] = make_uint2(h01, h23);
    ((uint2*)xl)[i] = make_uint2(l01, l23);
}

// ---------------- wk|wv -> fused B [256 x 512] bf16 hi/lo ----------------
__global__ __launch_bounds__(256) void cvt_w_kernel(const float* __restrict__ wk,
        const float* __restrict__ wv, ushort_t* __restrict__ bh, ushort_t* __restrict__ bl) {
    int idx = blockIdx.x * 256 + threadIdx.x;    // 131072 total
    int row = idx >> 9, col = idx & 511;
    float v = (col < 256) ? wk[row * 256 + col] : wv[row * 256 + col - 256];
    ushort_t h = f2bf(v);
    bh[idx] = h;
    bl[idx] = f2bf(v - bf2f(h));
}

// ---------------- zero the graph+mask tail of d_out (133 KB) ----------------
__global__ __launch_bounds__(256) void zero_tail_kernel(float4* __restrict__ p, int n4) {
    int i = blockIdx.x * 256 + threadIdx.x;
    if (i < n4) p[i] = make_float4(0.f, 0.f, 0.f, 0.f);
}

// ---------------- q = (lib @ wq) * rsqrt(DH) ----------------
__global__ __launch_bounds__(256) void qproj_kernel(const float* __restrict__ lib,
        const float* __restrict__ wq, float* __restrict__ q) {
    int m = blockIdx.x;            // 64
    int t = threadIdx.x;           // 256 output cols (h*32+dh)
    __shared__ float row[256];
    row[t] = lib[m * 256 + t];
    __syncthreads();
    float acc = 0.f;
    #pragma unroll 8
    for (int d = 0; d < 256; ++d) acc = fmaf(row[d], wq[d * 256 + t], acc);
    q[m * 256 + t] = acc * 0.17677669529663687f;   // 1/sqrt(32)
}

// ---------------- fused K|V projection: split-bf16 MFMA GEMM ----------------
// C[4096, 512] = x[4096,256] @ Bcat[256,512], 3 split terms via segment loop.
// BM=128, BN=64, BK=32; 256 threads = 4 waves (2x2), wave tile 64x32.
// grid = (4096/128, 512/64) = (32, 8). Cols 0-255 -> kbuf, 256-511 -> vbuf.
__global__ __launch_bounds__(256) void gemm_kv_mfma_kernel(
        const ushort_t* __restrict__ xh, const ushort_t* __restrict__ xl,
        const ushort_t* __restrict__ bh, const ushort_t* __restrict__ bl,
        float* __restrict__ kout, float* __restrict__ vout) {
    __shared__ ushort_t As[128][40];   // [m][k], +8 pad -> 80B rows (16B-aligned), <=2-way alias
    __shared__ ushort_t Bs[64][40];    // [n][k] (transposed so k is contiguous per lane)
    const int tid = threadIdx.x;
    const int w = tid >> 6, l = tid & 63;
    const int wr = w >> 1, wc = w & 1;           // 2x2 wave grid
    const int m0 = blockIdx.x * 128;
    const int n0 = blockIdx.y * 64;
    const int l15 = l & 15, lk8 = (l >> 4) * 8;

    const ushort_t* Aseg[3] = {xh, xl, xh};
    const ushort_t* Bseg[3] = {bh, bh, bl};

    f32x4 acc[4][2];
    #pragma unroll
    for (int i = 0; i < 4; ++i)
        #pragma unroll
        for (int j = 0; j < 2; ++j) acc[i][j] = (f32x4){0.f, 0.f, 0.f, 0.f};

    const int ar = tid >> 1, ah = (tid & 1) * 16;  // A: row, 16-ushort half
    const int bn = tid & 63, bk = tid >> 6;        // B: col, k-block of 8

    short8 areg0, areg1;
    ushort_t breg[8];
    #define PRELOAD(st) do { \
        int seg = (st) >> 3, k0 = ((st) & 7) << 5; \
        const ushort_t* Ap = Aseg[seg] + (size_t)(m0 + ar) * 256 + k0 + ah; \
        areg0 = *(const short8*)Ap; \
        areg1 = *(const short8*)(Ap + 8); \
        const ushort_t* Bp = Bseg[seg] + (size_t)(k0 + bk * 8) * 512 + n0 + bn; \
        _Pragma("unroll") \
        for (int j = 0; j < 8; ++j) breg[j] = Bp[(size_t)j * 512]; \
    } while (0)

    PRELOAD(0);
    for (int st = 0; st < 24; ++st) {
        __syncthreads();
        *(short8*)&As[ar][ah]     = areg0;
        *(short8*)&As[ar][ah + 8] = areg1;
        {
            short8 bv;
            #pragma unroll
            for (int j = 0; j < 8; ++j) bv[j] = (short)breg[j];
            *(short8*)&Bs[bn][bk * 8] = bv;
        }
        __syncthreads();
        if (st + 1 < 24) PRELOAD(st + 1);
        short8 a[4], b[2];
        #pragma unroll
        for (int i = 0; i < 4; ++i) a[i] = *(const short8*)&As[wr * 64 + i * 16 + l15][lk8];
        #pragma unroll
        for (int j = 0; j < 2; ++j) b[j] = *(const short8*)&Bs[wc * 32 + j * 16 + l15][lk8];
        #pragma unroll
        for (int i = 0; i < 4; ++i)
            #pragma unroll
            for (int j = 0; j < 2; ++j)
                acc[i][j] = __builtin_amdgcn_mfma_f32_16x16x32_bf16(a[i], b[j], acc[i][j], 0, 0, 0);
    }
    #undef PRELOAD

    // epilogue: C/D layout col=lane&15, row=(lane>>4)*4+reg [m89-verified]
    float* outp = (blockIdx.y < 4) ? kout : vout;
    const int nbase = (blockIdx.y < 4) ? n0 : (n0 - 256);
    #pragma unroll
    for (int i = 0; i < 4; ++i) {
        #pragma unroll
        for (int j = 0; j < 2; ++j) {
            int col = nbase + wc * 32 + j * 16 + l15;
            int rowb = m0 + wr * 64 + i * 16 + (l >> 4) * 4;
            #pragma unroll
            for (int r = 0; r < 4; ++r)
                outp[(size_t)(rowb + r) * 256 + col] = acc[i][j][r];
        }
    }
}

// ---------------- generic fp32 tiled GEMM (kept for ctx @ wo) ----------------
__global__ __launch_bounds__(256) void gemm_f32_kernel(const float* __restrict__ A,
        const float* __restrict__ Bm, float* __restrict__ C, int N, int K) {
    __shared__ float As[16][64];
    __shared__ float Bs[16][64];
    const int tid  = threadIdx.x;
    const int tr   = tid >> 4, tc = tid & 15;
    const int arow = tid >> 2, akq = (tid & 3) << 2;
    const int brow = tid >> 4, bnq = (tid & 15) << 2;
    float c[4][4] = {};
    const float* Ap = A + (size_t)(blockIdx.x * 64 + arow) * K + akq;
    const float* Bp = Bm + (size_t)brow * N + blockIdx.y * 64 + bnq;
    for (int k0 = 0; k0 < K; k0 += 16) {
        float4 av = *(const float4*)(Ap + k0);
        float4 bv = *(const float4*)(Bp + (size_t)k0 * N);
        As[akq    ][arow] = av.x;
        As[akq + 1][arow] = av.y;
        As[akq + 2][arow] = av.z;
        As[akq + 3][arow] = av.w;
        *(float4*)&Bs[brow][bnq] = bv;
        __syncthreads();
        #pragma unroll
        for (int kk = 0; kk < 16; ++kk) {
            float4 a4 = *(const float4*)&As[kk][tr << 2];
            float4 b4 = *(const float4*)&Bs[kk][tc << 2];
            float aa[4] = {a4.x, a4.y, a4.z, a4.w};
            float bb[4] = {b4.x, b4.y, b4.z, b4.w};
            #pragma unroll
            for (int i = 0; i < 4; ++i)
                #pragma unroll
                for (int j = 0; j < 4; ++j)
                    c[i][j] = fmaf(aa[i], bb[j], c[i][j]);
        }
        __syncthreads();
    }
    float* Cp = C + (size_t)(blockIdx.x * 64 + (tr << 2)) * N + blockIdx.y * 64 + (tc << 2);
    #pragma unroll
    for (int i = 0; i < 4; ++i)
        *(float4*)(Cp + (size_t)i * N) = make_float4(c[i][0], c[i][1], c[i][2], c[i][3]);
}

// ---------------- attention partials ----------------
__global__ __launch_bounds__(256) void attn_partial_kernel(const float* __restrict__ q,
        const float* __restrict__ k, const float* __restrict__ v, float* __restrict__ part) {
    const int bh = blockIdx.x;            // 0..63
    const int sq = blockIdx.y;            // 0..3
    const int b = bh >> 3, h = bh & 7;
    const int w = threadIdx.x >> 6;       // wave 0..3
    const int m = threadIdx.x & 63;       // query index
    const int s0 = sq * 128 + w * 32;

    float qr[32];
    {
        const float4* qp = (const float4*)(q + m * 256 + h * 32);
        #pragma unroll
        for (int u = 0; u < 8; ++u) {
            float4 t = qp[u];
            qr[4*u] = t.x; qr[4*u+1] = t.y; qr[4*u+2] = t.z; qr[4*u+3] = t.w;
        }
    }
    const float* kbase = k + ((size_t)(b * 512 + s0)) * 256 + h * 32;
    const float* vbase = v + ((size_t)(b * 512 + s0)) * 256 + h * 32;

    float Mx = -1e30f, sum = 0.f, acc[32];
    #pragma unroll
    for (int dh = 0; dh < 32; ++dh) acc[dh] = 0.f;

    #pragma unroll
    for (int cc = 0; cc < 4; ++cc) {
        float sc[8];
        #pragma unroll
        for (int i = 0; i < 8; ++i) {
            const float4* kr = (const float4*)(kbase + (size_t)(cc * 8 + i) * 256);
            float dsum = 0.f;
            #pragma unroll
            for (int u = 0; u < 8; ++u) {
                float4 kv = kr[u];
                dsum = fmaf(qr[4*u],   kv.x, dsum);
                dsum = fmaf(qr[4*u+1], kv.y, dsum);
                dsum = fmaf(qr[4*u+2], kv.z, dsum);
                dsum = fmaf(qr[4*u+3], kv.w, dsum);
            }
            sc[i] = dsum;
        }
        float cm = sc[0];
        #pragma unroll
        for (int i = 1; i < 8; ++i) cm = fmaxf(cm, sc[i]);
        float nm = fmaxf(Mx, cm);
        float f = __expf(Mx - nm);
        sum *= f;
        #pragma unroll
        for (int dh = 0; dh < 32; ++dh) acc[dh] *= f;
        #pragma unroll
        for (int i = 0; i < 8; ++i) {
            float p = __expf(sc[i] - nm);
            sum += p;
            const float4* vr = (const float4*)(vbase + (size_t)(cc * 8 + i) * 256);
            #pragma unroll
            for (int u = 0; u < 8; ++u) {
                float4 vv = vr[u];
                acc[4*u]   = fmaf(p, vv.x, acc[4*u]);
                acc[4*u+1] = fmaf(p, vv.y, acc[4*u+1]);
                acc[4*u+2] = fmaf(p, vv.z, acc[4*u+2]);
                acc[4*u+3] = fmaf(p, vv.w, acc[4*u+3]);
            }
        }
        Mx = nm;
    }
    float* pp = part + ((size_t)((bh * 4 + sq) * 4 + w) * 64 + m) * 36;
    #pragma unroll
    for (int u = 0; u < 8; ++u)
        *(float4*)(pp + 4 * u) = make_float4(acc[4*u], acc[4*u+1], acc[4*u+2], acc[4*u+3]);
    pp[32] = Mx; pp[33] = sum;
}

// ---------------- combine 16 partials -> ctx[b,m,h,dh] ----------------
__global__ __launch_bounds__(256) void attn_combine_kernel(const float* __restrict__ part,
        float* __restrict__ ctx) {
    const int bh = blockIdx.x;
    const int b = bh >> 3, h = bh & 7;
    const int t = threadIdx.x;
    const int m = t >> 2, g = t & 3;
    const float* pb = part + (size_t)bh * 16 * 64 * 36 + m * 36;
    float Mj[16], Sj[16];
    float Mx = -1e30f;
    #pragma unroll
    for (int j = 0; j < 16; ++j) {
        Mj[j] = pb[(size_t)j * 64 * 36 + 32];
        Sj[j] = pb[(size_t)j * 64 * 36 + 33];
        Mx = fmaxf(Mx, Mj[j]);
    }
    float wgt[16]; float Ssum = 0.f;
    #pragma unroll
    for (int j = 0; j < 16; ++j) { wgt[j] = __expf(Mj[j] - Mx); Ssum = fmaf(wgt[j], Sj[j], Ssum); }
    float inv = 1.f / Ssum;
    float* op = ctx + ((size_t)(b * 64 + m)) * 256 + h * 32 + g * 8;
    #pragma unroll
    for (int u = 0; u < 8; ++u) {
        float num = 0.f;
        #pragma unroll
        for (int j = 0; j < 16; ++j) num = fmaf(wgt[j], pb[(size_t)j * 64 * 36 + g * 8 + u], num);
        op[u] = num * inv;
    }
}

extern "C" void kernel_launch(void* const* d_in, const int* in_sizes, int n_in,
                              void* d_out, int out_size, void* d_ws, size_t ws_size,
                              hipStream_t stream) {
    const float* emb = (const float*)d_in[0];
    const float* lib = (const float*)d_in[2];
    const float* pos = (const float*)d_in[3];
    const float* wq  = (const float*)d_in[4];
    const float* wk  = (const float*)d_in[5];
    const float* wv  = (const float*)d_in[6];
    const float* wo  = (const float*)d_in[7];
    float* out = (float*)d_out;

    float* ws  = (float*)d_ws;
    float* kbuf = ws;                        // 1,048,576 f
    float* vbuf = kbuf + 1048576;            // 1,048,576 f
    float* qbuf = vbuf + 1048576;            // 16,384 f
    float* ctx  = qbuf + 16384;              // 131,072 f
    float* part = ctx + 131072;              // 2,359,296 f (peak region)
    // bf16 hi/lo buffers alias the part region (dead before attn_partial writes)
    ushort_t* xh = (ushort_t*)part;          // 1,048,576 us (2MB)
    ushort_t* xl = xh + 1048576;             // 1,048,576 us
    ushort_t* bh = xl + 1048576;             // 131,072 us
    ushort_t* bl = bh + 131072;              // 131,072 us  (total 4.7MB < part's 9.4MB)

    add_pos_cvt_kernel<<<1024, 256, 0, stream>>>(emb, pos, xh, xl);
    cvt_w_kernel<<<512, 256, 0, stream>>>(wk, wv, bh, bl);
    qproj_kernel<<<64, 256, 0, stream>>>(lib, wq, qbuf);
    zero_tail_kernel<<<33, 256, 0, stream>>>((float4*)(out + 131072), 8320);

    gemm_kv_mfma_kernel<<<dim3(32, 8), 256, 0, stream>>>(xh, xl, bh, bl, kbuf, vbuf);

    attn_partial_kernel<<<dim3(64, 4), 256, 0, stream>>>(qbuf, kbuf, vbuf, part);
    attn_combine_kernel<<<64, 256, 0, stream>>>(part, ctx);

    gemm_f32_kernel<<<dim3(8, 4), 256, 0, stream>>>(ctx, wo, out, 256, 256);
}